// Round 1
// baseline (1190.088 us; speedup 1.0000x reference)
//
#include <hip/hip_runtime.h>

#define N_NODES 100000
#define N_EDGES 1250000
#define D 64

// ---------------------------------------------------------------------------
// K1: zero the output accumulator (harness poisons d_out with 0xAA each call)
// ---------------------------------------------------------------------------
__global__ __launch_bounds__(256) void zero_out_kernel(float4* __restrict__ out4) {
    int i = blockIdx.x * 256 + threadIdx.x;
    if (i < N_NODES * (D / 4)) {
        out4[i] = make_float4(0.f, 0.f, 0.f, 0.f);
    }
}

// ---------------------------------------------------------------------------
// K2: fused gather * e -> atomic scatter-add into out (= ft accumulator)
// 16 lanes per edge; each lane handles one float4 (4 consecutive d's).
// ---------------------------------------------------------------------------
__global__ __launch_bounds__(256) void scatter_edges_kernel(
    const float* __restrict__ h,
    const float* __restrict__ e,
    const int* __restrict__ src,
    const int* __restrict__ dst,
    float* __restrict__ out) {
    int tid = blockIdx.x * 256 + threadIdx.x;
    int eid = tid >> 4;       // 16 threads per edge
    int l4  = tid & 15;       // which float4 of the 64-float row
    if (eid >= N_EDGES) return;

    int s = src[eid];
    int t = dst[eid];
    float w = e[eid];

    const float4* hrow = (const float4*)(h + s * D);
    float4 v = hrow[l4];

    float* op = out + t * D + l4 * 4;
    unsafeAtomicAdd(op + 0, v.x * w);
    unsafeAtomicAdd(op + 1, v.y * w);
    unsafeAtomicAdd(op + 2, v.z * w);
    unsafeAtomicAdd(op + 3, v.w * w);
}

// ---------------------------------------------------------------------------
// K3: in-place per-row linear: out_row = ft_row @ W^T + b
// One thread per node; row held in 16 float4 registers; W reads are
// wave-uniform (compiler scalarizes / L1 broadcast).
// ---------------------------------------------------------------------------
__global__ __launch_bounds__(256) void linear_inplace_kernel(
    float* __restrict__ io,
    const float* __restrict__ W,
    const float* __restrict__ b) {
    int n = blockIdx.x * 256 + threadIdx.x;
    if (n >= N_NODES) return;

    float4* row = (float4*)(io + n * D);
    float4 f[16];
#pragma unroll
    for (int i = 0; i < 16; ++i) f[i] = row[i];

#pragma unroll 1
    for (int o4 = 0; o4 < 16; ++o4) {
        const float4* w0 = (const float4*)(W + (o4 * 4 + 0) * D);
        const float4* w1 = (const float4*)(W + (o4 * 4 + 1) * D);
        const float4* w2 = (const float4*)(W + (o4 * 4 + 2) * D);
        const float4* w3 = (const float4*)(W + (o4 * 4 + 3) * D);
        float a0 = b[o4 * 4 + 0];
        float a1 = b[o4 * 4 + 1];
        float a2 = b[o4 * 4 + 2];
        float a3 = b[o4 * 4 + 3];
#pragma unroll
        for (int i = 0; i < 16; ++i) {
            float4 fv = f[i];
            float4 x0 = w0[i];
            float4 x1 = w1[i];
            float4 x2 = w2[i];
            float4 x3 = w3[i];
            a0 += fv.x * x0.x + fv.y * x0.y + fv.z * x0.z + fv.w * x0.w;
            a1 += fv.x * x1.x + fv.y * x1.y + fv.z * x1.z + fv.w * x1.w;
            a2 += fv.x * x2.x + fv.y * x2.y + fv.z * x2.z + fv.w * x2.w;
            a3 += fv.x * x3.x + fv.y * x3.y + fv.z * x3.z + fv.w * x3.w;
        }
        row[o4] = make_float4(a0, a1, a2, a3);
    }
}

// ---------------------------------------------------------------------------
extern "C" void kernel_launch(void* const* d_in, const int* in_sizes, int n_in,
                              void* d_out, int out_size, void* d_ws, size_t ws_size,
                              hipStream_t stream) {
    const float* h   = (const float*)d_in[0];
    const float* e   = (const float*)d_in[1];
    const int*   src = (const int*)d_in[2];
    const int*   dst = (const int*)d_in[3];
    const float* W   = (const float*)d_in[4];
    const float* b   = (const float*)d_in[5];
    float* out = (float*)d_out;

    // K1: zero ft accumulator
    {
        int total = N_NODES * (D / 4);
        int blocks = (total + 255) / 256;
        zero_out_kernel<<<blocks, 256, 0, stream>>>((float4*)out);
    }
    // K2: fused gather/scale/scatter-add
    {
        long long total = (long long)N_EDGES * 16;
        int blocks = (int)((total + 255) / 256);
        scatter_edges_kernel<<<blocks, 256, 0, stream>>>(h, e, src, dst, out);
    }
    // K3: in-place linear + bias
    {
        int blocks = (N_NODES + 255) / 256;
        linear_inplace_kernel<<<blocks, 256, 0, stream>>>(out, W, b);
    }
}

// Round 2
// 332.165 us; speedup vs baseline: 3.5828x; 3.5828x over previous
//
#include <hip/hip_runtime.h>

#define N_NODES 100000
#define N_EDGES 1250000
#define D 64
#define NBLK_N 391          // ceil(N_NODES/256)
#define NBLK_E 4883         // ceil(N_EDGES/256)

// ---------------------------------------------------------------------------
// Workspace layout (bytes, all 16B-aligned):
//   g        : N*64 f32   = 25,600,000      (h @ W^T)
//   counts   : N   i32    =    400,000      (in-degree)
//   starts   : N   i32    =    400,000      (CSR row starts)
//   cursor   : N   i32    =    400,000      (mutable copy for perm scatter)
//   bsums    : 391 i32    (padded)          (scan block sums)
//   src_s    : E   i32    =  5,000,000      (src sorted by dst)
//   e_s      : E   f32    =  5,000,000      (e   sorted by dst)
// total ~= 36.8 MB
// ---------------------------------------------------------------------------

__global__ __launch_bounds__(256) void zero_counts_kernel(int* __restrict__ counts) {
    int i = blockIdx.x * 256 + threadIdx.x;
    if (i < N_NODES) counts[i] = 0;
}

__global__ __launch_bounds__(256) void histogram_kernel(const int* __restrict__ dst,
                                                        int* __restrict__ counts) {
    int i = blockIdx.x * 256 + threadIdx.x;
    if (i < N_EDGES) atomicAdd(&counts[dst[i]], 1);
}

// Per-block exclusive scan of counts -> starts (block-local), block totals -> bsums
__global__ __launch_bounds__(256) void block_scan_kernel(const int* __restrict__ counts,
                                                         int* __restrict__ starts,
                                                         int* __restrict__ bsums) {
    __shared__ int tmp[256];
    int t = threadIdx.x;
    int i = blockIdx.x * 256 + t;
    int v = (i < N_NODES) ? counts[i] : 0;
    tmp[t] = v;
    __syncthreads();
#pragma unroll
    for (int off = 1; off < 256; off <<= 1) {
        int x = (t >= off) ? tmp[t - off] : 0;
        __syncthreads();
        tmp[t] += x;
        __syncthreads();
    }
    if (i < N_NODES) starts[i] = tmp[t] - v;   // exclusive within block
    if (t == 255) bsums[blockIdx.x] = tmp[255];
}

// Single-block exclusive scan of the 391 block sums (512 >= NBLK_N)
__global__ __launch_bounds__(512) void sum_scan_kernel(int* __restrict__ bsums) {
    __shared__ int tmp[512];
    int t = threadIdx.x;
    int v = (t < NBLK_N) ? bsums[t] : 0;
    tmp[t] = v;
    __syncthreads();
#pragma unroll
    for (int off = 1; off < 512; off <<= 1) {
        int x = (t >= off) ? tmp[t - off] : 0;
        __syncthreads();
        tmp[t] += x;
        __syncthreads();
    }
    if (t < NBLK_N) bsums[t] = tmp[t] - v;     // exclusive
}

__global__ __launch_bounds__(256) void add_offsets_kernel(int* __restrict__ starts,
                                                          const int* __restrict__ bsums,
                                                          int* __restrict__ cursor) {
    int i = blockIdx.x * 256 + threadIdx.x;
    if (i < N_NODES) {
        int s = starts[i] + bsums[blockIdx.x];
        starts[i] = s;
        cursor[i] = s;
    }
}

// Permute edges into dst-sorted order (counting-sort scatter).
__global__ __launch_bounds__(256) void scatter_perm_kernel(const int* __restrict__ src,
                                                           const int* __restrict__ dst,
                                                           const float* __restrict__ e,
                                                           int* __restrict__ cursor,
                                                           int* __restrict__ src_s,
                                                           float* __restrict__ e_s) {
    int i = blockIdx.x * 256 + threadIdx.x;
    if (i < N_EDGES) {
        int t = dst[i];
        int pos = atomicAdd(&cursor[t], 1);
        src_s[pos] = src[i];
        e_s[pos] = e[i];
    }
}

// g = h @ W^T. Block = 256 threads handles 64 nodes; h-tile and W staged in
// LDS (rows padded to 17 float4 to break bank conflicts). Thread t computes
// node (t>>2), output chunk (t&3)*16..+15, writes 4 coalesced float4s.
__global__ __launch_bounds__(256) void transform_kernel(const float* __restrict__ h,
                                                        const float* __restrict__ W,
                                                        float* __restrict__ g) {
    __shared__ float4 hs[64 * 17];
    __shared__ float4 ws4[64 * 17];
    int t = threadIdx.x;
    int n0 = blockIdx.x * 64;
#pragma unroll
    for (int k = 0; k < 4; ++k) {
        int f = t + k * 256;            // 0..1023 = 64 rows x 16 float4
        int r = f >> 4, c = f & 15;
        float4 hv = make_float4(0.f, 0.f, 0.f, 0.f);
        if (n0 + r < N_NODES) hv = ((const float4*)h)[(n0 + r) * 16 + c];
        hs[r * 17 + c] = hv;
        ws4[r * 17 + c] = ((const float4*)W)[f];
    }
    __syncthreads();

    int r = t >> 2;          // local node 0..63
    int oq = t & 3;          // output quarter
    float acc[16];
#pragma unroll
    for (int j = 0; j < 16; ++j) acc[j] = 0.f;

    for (int d4 = 0; d4 < 16; ++d4) {
        float4 hv = hs[r * 17 + d4];
#pragma unroll
        for (int j = 0; j < 16; ++j) {
            float4 wv = ws4[(oq * 16 + j) * 17 + d4];
            acc[j] += hv.x * wv.x + hv.y * wv.y + hv.z * wv.z + hv.w * wv.w;
        }
    }

    int n = n0 + r;
    if (n < N_NODES) {
        float4* gr = (float4*)(g + n * D + oq * 16);
        gr[0] = make_float4(acc[0], acc[1], acc[2], acc[3]);
        gr[1] = make_float4(acc[4], acc[5], acc[6], acc[7]);
        gr[2] = make_float4(acc[8], acc[9], acc[10], acc[11]);
        gr[3] = make_float4(acc[12], acc[13], acc[14], acc[15]);
    }
}

// One wave per node: lane d accumulates out[n,d] = b[d] + sum_k e_k * g[src_k, d].
// g-row reads are coalesced 256B; src_s/e_s reads are wave-uniform (cache bcast).
__global__ __launch_bounds__(256) void gather_nodes_kernel(const float* __restrict__ g,
                                                           const int* __restrict__ src_s,
                                                           const float* __restrict__ e_s,
                                                           const int* __restrict__ starts,
                                                           const int* __restrict__ counts,
                                                           const float* __restrict__ b,
                                                           float* __restrict__ out) {
    int w = (blockIdx.x * 256 + threadIdx.x) >> 6;   // node id
    int lane = threadIdx.x & 63;
    if (w >= N_NODES) return;
    int start = starts[w];
    int end = start + counts[w];
    float acc = b[lane];
    int k = start;
    for (; k + 4 <= end; k += 4) {
        int s0 = src_s[k], s1 = src_s[k + 1], s2 = src_s[k + 2], s3 = src_s[k + 3];
        float w0 = e_s[k], w1 = e_s[k + 1], w2 = e_s[k + 2], w3 = e_s[k + 3];
        acc += w0 * g[s0 * D + lane];
        acc += w1 * g[s1 * D + lane];
        acc += w2 * g[s2 * D + lane];
        acc += w3 * g[s3 * D + lane];
    }
    for (; k < end; ++k) acc += e_s[k] * g[src_s[k] * D + lane];
    out[w * D + lane] = acc;
}

// ---------------------------------------------------------------------------
extern "C" void kernel_launch(void* const* d_in, const int* in_sizes, int n_in,
                              void* d_out, int out_size, void* d_ws, size_t ws_size,
                              hipStream_t stream) {
    const float* h   = (const float*)d_in[0];
    const float* e   = (const float*)d_in[1];
    const int*   src = (const int*)d_in[2];
    const int*   dst = (const int*)d_in[3];
    const float* W   = (const float*)d_in[4];
    const float* b   = (const float*)d_in[5];
    float* out = (float*)d_out;

    char* ws = (char*)d_ws;
    float* g      = (float*)(ws);                         // 25,600,000 B
    int*   counts = (int*)  (ws + 25600000);              //    400,000 B
    int*   starts = (int*)  (ws + 26000000);              //    400,000 B
    int*   cursor = (int*)  (ws + 26400000);              //    400,000 B
    int*   bsums  = (int*)  (ws + 26800000);              //      1,568 B (391 + pad)
    int*   src_s  = (int*)  (ws + 26801568);              //  5,000,000 B
    float* e_s    = (float*)(ws + 31801568);              //  5,000,000 B

    // transform can go first: independent of the sort pipeline
    transform_kernel<<<(N_NODES + 63) / 64, 256, 0, stream>>>(h, W, g);

    zero_counts_kernel<<<NBLK_N, 256, 0, stream>>>(counts);
    histogram_kernel<<<NBLK_E, 256, 0, stream>>>(dst, counts);
    block_scan_kernel<<<NBLK_N, 256, 0, stream>>>(counts, starts, bsums);
    sum_scan_kernel<<<1, 512, 0, stream>>>(bsums);
    add_offsets_kernel<<<NBLK_N, 256, 0, stream>>>(starts, bsums, cursor);
    scatter_perm_kernel<<<NBLK_E, 256, 0, stream>>>(src, dst, e, cursor, src_s, e_s);

    gather_nodes_kernel<<<(N_NODES * 64 + 255) / 256, 256, 0, stream>>>(
        g, src_s, e_s, starts, counts, b, out);
}